// Round 1
// baseline (3752.192 us; speedup 1.0000x reference)
//
#include <hip/hip_runtime.h>

// ---------------------------------------------------------------------------
// Weight norm: out[row] = v[row] * g[row]/||v[row]||, row length = len
// ---------------------------------------------------------------------------
__global__ __launch_bounds__(256) void wn_kernel(const float* __restrict__ v,
                                                 const float* __restrict__ g,
                                                 float* __restrict__ out, int len) {
    __shared__ float red[4];
    __shared__ float s_scale;
    int row = blockIdx.x;
    const float* vr = v + (size_t)row * len;
    float ss = 0.f;
    for (int i = threadIdx.x; i < len; i += 256) { float a = vr[i]; ss += a * a; }
    for (int o = 32; o > 0; o >>= 1) ss += __shfl_down(ss, o);
    if ((threadIdx.x & 63) == 0) red[threadIdx.x >> 6] = ss;
    __syncthreads();
    if (threadIdx.x == 0) s_scale = g[row] / sqrtf(red[0] + red[1] + red[2] + red[3]);
    __syncthreads();
    float sc = s_scale;
    float* orow = out + (size_t)row * len;
    for (int i = threadIdx.x; i < len; i += 256) orow[i] = vr[i] * sc;
}

// ---------------------------------------------------------------------------
// Per-(b,ch) spatial mean over 64x64 = 4096 elements. grid.x = B*CH
// ---------------------------------------------------------------------------
__global__ __launch_bounds__(256) void mean_kernel(const float* __restrict__ in,
                                                   float* __restrict__ out) {
    __shared__ float red[4];
    int row = blockIdx.x;
    const float* p = in + (size_t)row * 4096;
    float s = 0.f;
    for (int i = threadIdx.x; i < 4096; i += 256) s += p[i];
    for (int o = 32; o > 0; o >>= 1) s += __shfl_down(s, o);
    if ((threadIdx.x & 63) == 0) red[threadIdx.x >> 6] = s;
    __syncthreads();
    if (threadIdx.x == 0) out[row] = (red[0] + red[1] + red[2] + red[3]) * (1.f / 4096.f);
}

// ---------------------------------------------------------------------------
// Routing: logits[b][j] = mean[b]·mw[j] + mb[j]; softmax over g (j = g*4+c).
// 1 block, 64 threads (b = tid>>3, j = tid&7). s_out[b*8 + j].
// ---------------------------------------------------------------------------
__global__ void route_kernel(const float* __restrict__ mean, const float* __restrict__ mw,
                             const float* __restrict__ mb, float* __restrict__ s_out, int IC) {
    __shared__ float lg[64];
    int tid = threadIdx.x;
    int b = tid >> 3, j = tid & 7;
    float acc = mb[j];
    for (int i = 0; i < IC; ++i) acc += mean[b * IC + i] * mw[j * IC + i];
    lg[tid] = acc;
    __syncthreads();
    int g = j >> 2, c = j & 3;
    float l0 = lg[b * 8 + c], l1 = lg[b * 8 + 4 + c];
    float m = fmaxf(l0, l1);
    float e0 = __expf(l0 - m), e1 = __expf(l1 - m);
    float mine = (g == 0) ? e0 : e1;
    s_out[tid] = mine / (e0 + e1);
}

// ---------------------------------------------------------------------------
// Per-sample weight combine: wper[b][oc][r] = s0*w[oc][r] + s1*w[OC+oc][r]
// (row (g*C+c)*D+d == g*OC + oc). total = 8*OC*ICx9 elements.
// ---------------------------------------------------------------------------
__global__ __launch_bounds__(256) void combine_w_kernel(const float* __restrict__ w,
                                                        const float* __restrict__ s,
                                                        float* __restrict__ wper,
                                                        int D, int ICx9, int OC) {
    int idx = blockIdx.x * 256 + threadIdx.x;
    int total = 8 * OC * ICx9;
    if (idx >= total) return;
    int r = idx % ICx9;
    int tmp = idx / ICx9;
    int oc = tmp % OC;
    int b = tmp / OC;
    int c = oc / D;
    float s0 = s[b * 8 + c], s1 = s[b * 8 + 4 + c];
    wper[idx] = s0 * w[(size_t)oc * ICx9 + r] + s1 * w[(size_t)(OC + oc) * ICx9 + r];
}

__global__ void combine_b_kernel(const float* __restrict__ bias, const float* __restrict__ s,
                                 float* __restrict__ bper, int D, int OC) {
    int idx = blockIdx.x * 256 + threadIdx.x;  // < 8*OC (exact grid)
    int oc = idx % OC;
    int b = idx / OC;
    int c = oc / D;
    bper[idx] = s[b * 8 + c] * bias[oc] + s[b * 8 + 4 + c] * bias[OC + oc];
}

// ---------------------------------------------------------------------------
// Direct 3x3 conv, pad=1, 64x64 image. 256 threads: 16x16, each 2x2 pixels,
// OCT output channels. Per input channel: stage 34x34 halo tile + OCT*9
// weights into LDS, accumulate in registers.
//   grid = (4 spatial tiles, OC/OCT, B)
//   wstride_b/bstride_b = 0 for shared weights, per-sample stride otherwise.
// ---------------------------------------------------------------------------
template <int OCT>
__global__ __launch_bounds__(256) void conv3x3(
    const float* __restrict__ in, const float* __restrict__ w,
    const float* __restrict__ bias, const float* __restrict__ residual,
    float* __restrict__ out, int IC, int OC, long wstride_b, int bstride_b,
    float in_off, int do_relu) {
    __shared__ float s_in[34 * 34];
    __shared__ float s_w[OCT * 9];
    int b = blockIdx.z;
    int ocBase = blockIdx.y * OCT;
    int ty0 = (blockIdx.x >> 1) * 32;
    int tx0 = (blockIdx.x & 1) * 32;
    int tid = threadIdx.x;
    int tx = tid & 15, ty = tid >> 4;

    float acc[OCT][4];
#pragma unroll
    for (int oc = 0; oc < OCT; ++oc)
#pragma unroll
        for (int p = 0; p < 4; ++p) acc[oc][p] = 0.f;

    const float* inb = in + (size_t)b * IC * 4096;
    const float* wb = w + (size_t)b * wstride_b;

    for (int ic = 0; ic < IC; ++ic) {
        const float* src = inb + (size_t)ic * 4096;
        for (int i = tid; i < 34 * 34; i += 256) {
            int r = i / 34, cc = i % 34;
            int gy = ty0 + r - 1, gx = tx0 + cc - 1;
            float val = 0.f;
            if (gy >= 0 && gy < 64 && gx >= 0 && gx < 64) val = src[gy * 64 + gx] + in_off;
            s_in[i] = val;
        }
        for (int i = tid; i < OCT * 9; i += 256) {
            int oc = i / 9, t = i % 9;
            float wv = 0.f;
            if (ocBase + oc < OC) wv = wb[((size_t)(ocBase + oc) * IC + ic) * 9 + t];
            s_w[i] = wv;
        }
        __syncthreads();

        float v[4][4];
#pragma unroll
        for (int r = 0; r < 4; ++r)
#pragma unroll
            for (int cc = 0; cc < 4; ++cc) v[r][cc] = s_in[(2 * ty + r) * 34 + (2 * tx + cc)];

#pragma unroll
        for (int oc = 0; oc < OCT; ++oc) {
#pragma unroll
            for (int ky = 0; ky < 3; ++ky)
#pragma unroll
                for (int kx = 0; kx < 3; ++kx) {
                    float wv = s_w[oc * 9 + ky * 3 + kx];
                    acc[oc][0] += wv * v[ky][kx];
                    acc[oc][1] += wv * v[ky][kx + 1];
                    acc[oc][2] += wv * v[ky + 1][kx];
                    acc[oc][3] += wv * v[ky + 1][kx + 1];
                }
        }
        __syncthreads();
    }

    int py = ty0 + 2 * ty, px = tx0 + 2 * tx;
#pragma unroll
    for (int oc = 0; oc < OCT; ++oc) {
        int og = ocBase + oc;
        if (og >= OC) continue;
        float bv = bias[(size_t)b * bstride_b + og];
        size_t base = (((size_t)b * OC + og) * 64 + py) * 64 + px;
#pragma unroll
        for (int p = 0; p < 4; ++p) {
            int dy = p >> 1, dx = p & 1;
            float val = acc[oc][p] + bv;
            if (do_relu) val = fmaxf(val, 0.f);
            size_t o = base + (size_t)dy * 64 + dx;
            if (residual) val += residual[o];
            out[o] = val;
        }
    }
}

// ---------------------------------------------------------------------------
// Skip conv: 5x5, pad=2, IC=3, OC=12, input offset -0.5. Naive per-pixel.
// ---------------------------------------------------------------------------
__global__ __launch_bounds__(256) void skip_conv_kernel(const float* __restrict__ x,
                                                        const float* __restrict__ w,
                                                        const float* __restrict__ bias,
                                                        float* __restrict__ out) {
    int idx = blockIdx.x * 256 + threadIdx.x;  // 8*12*4096
    int px = idx & 63;
    int py = (idx >> 6) & 63;
    int v = idx >> 12;
    int oc = v % 12;
    int b = v / 12;
    float acc = bias[oc];
    for (int ic = 0; ic < 3; ++ic)
        for (int ky = 0; ky < 5; ++ky) {
            int gy = py + ky - 2;
            if (gy < 0 || gy >= 64) continue;
            for (int kx = 0; kx < 5; ++kx) {
                int gx = px + kx - 2;
                if (gx < 0 || gx >= 64) continue;
                acc += w[((oc * 3 + ic) * 5 + ky) * 5 + kx] *
                       (x[((size_t)(b * 3 + ic) * 64 + gy) * 64 + gx] - 0.5f);
            }
        }
    out[idx] = acc;
}

// ---------------------------------------------------------------------------
// Pixel shuffle (r=2) + add + IMAGE_MEAN. out [8,3,128,128]
// ---------------------------------------------------------------------------
__global__ __launch_bounds__(256) void shuffle_kernel(const float* __restrict__ body,
                                                      const float* __restrict__ skipb,
                                                      float* __restrict__ out) {
    int idx = blockIdx.x * 256 + threadIdx.x;  // 8*3*128*128
    int ox = idx & 127;
    int oy = (idx >> 7) & 127;
    int v = idx >> 14;
    int c = v % 3;
    int b = v / 3;
    int rx = ox & 1, ry = oy & 1;
    int xx = ox >> 1, yy = oy >> 1;
    int ch = c * 4 + ry * 2 + rx;
    size_t src = (((size_t)b * 12 + ch) * 64 + yy) * 64 + xx;
    out[idx] = body[src] + skipb[src] + 0.5f;
}

// ---------------------------------------------------------------------------
extern "C" void kernel_launch(void* const* d_in, const int* in_sizes, int n_in,
                              void* d_out, int out_size, void* d_ws, size_t ws_size,
                              hipStream_t stream) {
    const float* x      = (const float*)d_in[0];
    const float* head_v = (const float*)d_in[1];
    const float* head_g = (const float*)d_in[2];
    const float* head_b = (const float*)d_in[3];
    const float* b1_v   = (const float*)d_in[4];
    const float* b1_g   = (const float*)d_in[5];
    const float* b1_b   = (const float*)d_in[6];
    const float* b1_mw  = (const float*)d_in[7];
    const float* b1_mb  = (const float*)d_in[8];
    const float* b2_v   = (const float*)d_in[9];
    const float* b2_g   = (const float*)d_in[10];
    const float* b2_b   = (const float*)d_in[11];
    const float* b2_mw  = (const float*)d_in[12];
    const float* b2_mb  = (const float*)d_in[13];
    const float* tail_v = (const float*)d_in[14];
    const float* tail_g = (const float*)d_in[15];
    const float* tail_b = (const float*)d_in[16];
    const float* skip_v = (const float*)d_in[17];
    const float* skip_g = (const float*)d_in[18];
    const float* skip_b = (const float*)d_in[19];

    float* ws = (float*)d_ws;
    size_t off = 0;
    auto alloc = [&](size_t n) { float* p = ws + off; off += n; return p; };
    float* head_w = alloc(64 * 27);
    float* b1_w   = alloc((size_t)2048 * 576);
    float* b2_w   = alloc((size_t)512 * 2304);
    float* tail_w = alloc(12 * 576);
    float* skip_w = alloc(12 * 75);
    float* h      = alloc((size_t)8 * 64 * 4096);
    float* t      = alloc((size_t)8 * 256 * 4096);
    float* meanb  = alloc(2048);
    float* sbuf   = alloc(64);
    float* wper1  = alloc((size_t)8 * 256 * 576);
    float* bper1  = alloc(2048);
    float* wper2  = alloc((size_t)8 * 64 * 2304);
    float* bper2  = alloc(512);
    float* body   = alloc((size_t)8 * 12 * 4096);
    float* skipb  = alloc((size_t)8 * 12 * 4096);
    (void)ws_size; (void)in_sizes; (void)n_in; (void)out_size;

    // Weight norms
    wn_kernel<<<64, 256, 0, stream>>>(head_v, head_g, head_w, 27);
    wn_kernel<<<2048, 256, 0, stream>>>(b1_v, b1_g, b1_w, 576);
    wn_kernel<<<512, 256, 0, stream>>>(b2_v, b2_g, b2_w, 2304);
    wn_kernel<<<12, 256, 0, stream>>>(tail_v, tail_g, tail_w, 576);
    wn_kernel<<<12, 256, 0, stream>>>(skip_v, skip_g, skip_w, 75);

    // Head: 3 -> 64, input x - 0.5
    conv3x3<16><<<dim3(4, 4, 8), 256, 0, stream>>>(x, head_w, head_b, nullptr, h,
                                                   3, 64, 0, 0, -0.5f, 0);

    for (int l = 0; l < 4; ++l) {
        // dyn conv 1: 64 -> 256, relu
        mean_kernel<<<512, 256, 0, stream>>>(h, meanb);
        route_kernel<<<1, 64, 0, stream>>>(meanb, b1_mw + (size_t)l * 8 * 64,
                                           b1_mb + l * 8, sbuf, 64);
        combine_w_kernel<<<4608, 256, 0, stream>>>(b1_w + (size_t)l * 512 * 576, sbuf,
                                                   wper1, 64, 576, 256);
        combine_b_kernel<<<8, 256, 0, stream>>>(b1_b + l * 512, sbuf, bper1, 64, 256);
        conv3x3<16><<<dim3(4, 16, 8), 256, 0, stream>>>(h, wper1, bper1, nullptr, t,
                                                        64, 256, 256 * 576, 256, 0.f, 1);
        // dyn conv 2: 256 -> 64, + residual h
        mean_kernel<<<2048, 256, 0, stream>>>(t, meanb);
        route_kernel<<<1, 64, 0, stream>>>(meanb, b2_mw + (size_t)l * 8 * 256,
                                           b2_mb + l * 8, sbuf, 256);
        combine_w_kernel<<<4608, 256, 0, stream>>>(b2_w + (size_t)l * 128 * 2304, sbuf,
                                                   wper2, 16, 2304, 64);
        combine_b_kernel<<<2, 256, 0, stream>>>(b2_b + l * 128, sbuf, bper2, 16, 64);
        conv3x3<8><<<dim3(4, 8, 8), 256, 0, stream>>>(t, wper2, bper2, h, h,
                                                      256, 64, 64 * 2304, 64, 0.f, 0);
    }

    // Tail: 64 -> 12
    conv3x3<4><<<dim3(4, 3, 8), 256, 0, stream>>>(h, tail_w, tail_b, nullptr, body,
                                                  64, 12, 0, 0, 0.f, 0);
    // Skip: 3 -> 12, 5x5
    skip_conv_kernel<<<1536, 256, 0, stream>>>(x, skip_w, skip_b, skipb);
    // Pixel shuffle + mean
    shuffle_kernel<<<1536, 256, 0, stream>>>(body, skipb, (float*)d_out);
}

// Round 2
// 693.107 us; speedup vs baseline: 5.4136x; 5.4136x over previous
//
#include <hip/hip_runtime.h>

typedef __attribute__((ext_vector_type(8))) short bf16x8;
typedef __attribute__((ext_vector_type(4))) float f32x4;

__device__ inline unsigned short bf16u(float x) {
    unsigned int u = __builtin_bit_cast(unsigned int, x);
    unsigned int r = (u + 0x7fffu + ((u >> 16) & 1u)) >> 16;
    return (unsigned short)r;
}

// ---------------------------------------------------------------------------
// Weight norm: out[row] = v[row] * g[row]/||v[row]||, row length = len
// ---------------------------------------------------------------------------
__global__ __launch_bounds__(256) void wn_kernel(const float* __restrict__ v,
                                                 const float* __restrict__ g,
                                                 float* __restrict__ out, int len) {
    __shared__ float red[4];
    __shared__ float s_scale;
    int row = blockIdx.x;
    const float* vr = v + (size_t)row * len;
    float ss = 0.f;
    for (int i = threadIdx.x; i < len; i += 256) { float a = vr[i]; ss += a * a; }
    for (int o = 32; o > 0; o >>= 1) ss += __shfl_down(ss, o);
    if ((threadIdx.x & 63) == 0) red[threadIdx.x >> 6] = ss;
    __syncthreads();
    if (threadIdx.x == 0) s_scale = g[row] / sqrtf(red[0] + red[1] + red[2] + red[3]);
    __syncthreads();
    float sc = s_scale;
    float* orow = out + (size_t)row * len;
    for (int i = threadIdx.x; i < len; i += 256) orow[i] = vr[i] * sc;
}

// ---------------------------------------------------------------------------
// Per-(b,ch) spatial mean over 64x64. grid.x = B*CH
// ---------------------------------------------------------------------------
__global__ __launch_bounds__(256) void mean_kernel(const float* __restrict__ in,
                                                   float* __restrict__ out) {
    __shared__ float red[4];
    int row = blockIdx.x;
    const float* p = in + (size_t)row * 4096;
    float s = 0.f;
    for (int i = threadIdx.x; i < 4096; i += 256) s += p[i];
    for (int o = 32; o > 0; o >>= 1) s += __shfl_down(s, o);
    if ((threadIdx.x & 63) == 0) red[threadIdx.x >> 6] = s;
    __syncthreads();
    if (threadIdx.x == 0) out[row] = (red[0] + red[1] + red[2] + red[3]) * (1.f / 4096.f);
}

// ---------------------------------------------------------------------------
// Routing softmax over g. 1 block, 64 threads. s_out[b*8 + g*4 + c]
// ---------------------------------------------------------------------------
__global__ void route_kernel(const float* __restrict__ mean, const float* __restrict__ mw,
                             const float* __restrict__ mb, float* __restrict__ s_out, int IC) {
    __shared__ float lg[64];
    int tid = threadIdx.x;
    int b = tid >> 3, j = tid & 7;
    float acc = mb[j];
    for (int i = 0; i < IC; ++i) acc += mean[b * IC + i] * mw[j * IC + i];
    lg[tid] = acc;
    __syncthreads();
    int g = j >> 2, c = j & 3;
    float l0 = lg[b * 8 + c], l1 = lg[b * 8 + 4 + c];
    float m = fmaxf(l0, l1);
    float e0 = __expf(l0 - m), e1 = __expf(l1 - m);
    float mine = (g == 0) ? e0 : e1;
    s_out[tid] = mine / (e0 + e1);
}

// ---------------------------------------------------------------------------
// Per-sample weight combine, output bf16 pre-swizzled for MFMA A-fragments:
// wq[b][ot][kc][tap][kg][mo][kj], oc = ot*MT+mo, ic = kc*32+kg*8+kj.
// ---------------------------------------------------------------------------
__global__ __launch_bounds__(256) void combine_w_mfma(const float* __restrict__ w,
                                                      const float* __restrict__ s,
                                                      unsigned short* __restrict__ wq,
                                                      int D, int IC, int OC, int MT) {
    int idx = blockIdx.x * 256 + threadIdx.x;  // exact grid: 8*OC*IC*9
    int kj = idx & 7;
    int tmp = idx >> 3;
    int mo = tmp % MT; tmp /= MT;
    int kg = tmp & 3; tmp >>= 2;
    int t = tmp % 9; tmp /= 9;
    int KCh = IC >> 5;
    int kc = tmp % KCh; tmp /= KCh;
    int OT = OC / MT;
    int ot = tmp % OT;
    int b = tmp / OT;
    int oc = ot * MT + mo;
    int ic = kc * 32 + kg * 8 + kj;
    int c = oc / D;
    float s0 = s[b * 8 + c], s1 = s[b * 8 + 4 + c];
    float val = s0 * w[((size_t)oc * IC + ic) * 9 + t] +
                s1 * w[((size_t)(OC + oc) * IC + ic) * 9 + t];
    wq[idx] = bf16u(val);
}

__global__ void combine_b_kernel(const float* __restrict__ bias, const float* __restrict__ s,
                                 float* __restrict__ bper, int D, int OC) {
    int idx = blockIdx.x * 256 + threadIdx.x;  // exact grid: 8*OC
    int oc = idx % OC;
    int b = idx / OC;
    int c = oc / D;
    bper[idx] = s[b * 8 + c] * bias[oc] + s[b * 8 + 4 + c] * bias[OC + oc];
}

// ---------------------------------------------------------------------------
// MFMA implicit-GEMM 3x3 conv, pad=1, 64x64 images, per-sample weights.
//   block = 256 threads = 4 waves (2 M x 2 N)
//   block tile: MT output channels x (NR rows * 64 cols) pixels
//   K loop: 32-ic chunks x 9 taps. Input tile [NR+2][66][32] bf16 in LDS
//   (inner dim padded to 40 ushorts = 80B for bank spread). Weights staged
//   contiguous (already fragment-ordered by combine_w_mfma).
// ---------------------------------------------------------------------------
template <int IC, int OC, int MT, int NR, bool RELU, bool RES>
__global__ __launch_bounds__(256) void conv_mfma(
    const float* __restrict__ in, const unsigned short* __restrict__ wq,
    const float* __restrict__ bias, const float* __restrict__ res,
    float* __restrict__ out) {
    constexpr int KCH = IC / 32;
    constexpr int OT = OC / MT;
    constexpr int NRH = NR + 2;
    constexpr int NT = NR * 64;
    constexpr int NF = NR * 2;   // 16-px frags per wave (wave covers NT/2)
    constexpr int MW = MT / 32;  // 16-oc frags per wave (wave covers MT/2)
    constexpr int SROW = 40;     // padded ic-dim (80B)
    constexpr int WELEM = 9 * 4 * MT * 8;

    __shared__ unsigned short S[NRH * 66 * SROW];
    __shared__ unsigned short W[WELEM];

    int b = blockIdx.z, ot = blockIdx.y, strip = blockIdx.x;
    int y0 = strip * NR;
    int tid = threadIdx.x;
    int lane = tid & 63, wid = tid >> 6;
    int wm = wid >> 1, wn = wid & 1;
    int l15 = lane & 15, lk = lane >> 4;

    f32x4 acc[MW][NF];
#pragma unroll
    for (int mf = 0; mf < MW; ++mf)
#pragma unroll
        for (int nf = 0; nf < NF; ++nf)
#pragma unroll
            for (int q = 0; q < 4; ++q) acc[mf][nf][q] = 0.f;

    const float* inb = in + (size_t)b * IC * 4096;
    const unsigned short* wqb = wq + ((size_t)(b * OT + ot) * KCH) * WELEM;

    for (int kc = 0; kc < KCH; ++kc) {
        __syncthreads();
        // ---- stage weights (contiguous copy, 16B chunks) ----
        {
            const f32x4* src = (const f32x4*)(wqb + (size_t)kc * WELEM);
            f32x4* dst = (f32x4*)W;
            constexpr int NV = WELEM * 2 / 16;
#pragma unroll
            for (int i = 0; i < (NV + 255) / 256; ++i) {
                int j = i * 256 + tid;
                if (j < NV) dst[j] = src[j];
            }
        }
        // ---- stage input tile (cols 1..64 = x 0..63, aligned float4) ----
        {
            int icBase = kc * 32;
            for (int i = tid; i < 32 * NRH * 16; i += 256) {
                int cg = i & 15;
                int rk = i >> 4;
                int row = rk % NRH;
                int k = rk / NRH;
                int y = y0 + row - 1;
                unsigned short* dst = &S[(row * 66 + 1 + cg * 4) * SROW + k];
                if (y >= 0 && y < 64) {
                    const float4 v = *(const float4*)&inb[(size_t)(icBase + k) * 4096 + y * 64 + cg * 4];
                    dst[0] = bf16u(v.x);
                    dst[SROW] = bf16u(v.y);
                    dst[2 * SROW] = bf16u(v.z);
                    dst[3 * SROW] = bf16u(v.w);
                } else {
                    dst[0] = 0; dst[SROW] = 0; dst[2 * SROW] = 0; dst[3 * SROW] = 0;
                }
            }
            // zero halo cols 0 and 65 (x=-1 and x=64)
            for (int i = tid; i < 32 * NRH * 2; i += 256) {
                int e = i & 1;
                int rk = i >> 1;
                int row = rk % NRH;
                int k = rk / NRH;
                S[(row * 66 + e * 65) * SROW + k] = 0;
            }
        }
        __syncthreads();
        // ---- compute: 9 taps x NF x MW MFMAs ----
#pragma unroll
        for (int t = 0; t < 9; ++t) {
            const int dy = t / 3, dx = t % 3;
            bf16x8 a[MW];
#pragma unroll
            for (int mf = 0; mf < MW; ++mf) {
                int mo = wm * (MT / 2) + mf * 16 + l15;
                a[mf] = *(const bf16x8*)&W[((t * 4 + lk) * MT + mo) * 8];
            }
#pragma unroll
            for (int nf = 0; nf < NF; ++nf) {
                int n = wn * (NT / 2) + nf * 16 + l15;
                int r = n >> 6, c = n & 63;
                bf16x8 bf = *(const bf16x8*)&S[((r + dy) * 66 + (c + dx)) * SROW + lk * 8];
#pragma unroll
                for (int mf = 0; mf < MW; ++mf)
                    acc[mf][nf] = __builtin_amdgcn_mfma_f32_16x16x32_bf16(a[mf], bf, acc[mf][nf], 0, 0, 0);
            }
        }
    }
    // ---- epilogue: C/D layout col=lane&15, row=(lane>>4)*4+q ----
#pragma unroll
    for (int mf = 0; mf < MW; ++mf) {
        int ocb = ot * MT + wm * (MT / 2) + mf * 16 + lk * 4;
#pragma unroll
        for (int nf = 0; nf < NF; ++nf) {
            int n = wn * (NT / 2) + nf * 16 + l15;
            int y = y0 + (n >> 6), x = n & 63;
#pragma unroll
            for (int q = 0; q < 4; ++q) {
                int oc = ocb + q;
                size_t o = (((size_t)b * OC + oc) * 64 + y) * 64 + x;
                float v = acc[mf][nf][q] + bias[b * OC + oc];
                if (RELU) v = fmaxf(v, 0.f);
                if (RES) v += res[o];
                out[o] = v;
            }
        }
    }
}

// ---------------------------------------------------------------------------
// Direct 3x3 conv (kept for head/tail: small IC or OC)
// ---------------------------------------------------------------------------
template <int OCT>
__global__ __launch_bounds__(256) void conv3x3_direct(
    const float* __restrict__ in, const float* __restrict__ w,
    const float* __restrict__ bias, float* __restrict__ out, int IC, int OC,
    float in_off) {
    __shared__ float s_in[34 * 34];
    __shared__ float s_w[OCT * 9];
    int b = blockIdx.z;
    int ocBase = blockIdx.y * OCT;
    int ty0 = (blockIdx.x >> 1) * 32;
    int tx0 = (blockIdx.x & 1) * 32;
    int tid = threadIdx.x;
    int tx = tid & 15, ty = tid >> 4;

    float acc[OCT][4];
#pragma unroll
    for (int oc = 0; oc < OCT; ++oc)
#pragma unroll
        for (int p = 0; p < 4; ++p) acc[oc][p] = 0.f;

    const float* inb = in + (size_t)b * IC * 4096;

    for (int ic = 0; ic < IC; ++ic) {
        const float* src = inb + (size_t)ic * 4096;
        for (int i = tid; i < 34 * 34; i += 256) {
            int r = i / 34, cc = i % 34;
            int gy = ty0 + r - 1, gx = tx0 + cc - 1;
            float val = 0.f;
            if (gy >= 0 && gy < 64 && gx >= 0 && gx < 64) val = src[gy * 64 + gx] + in_off;
            s_in[i] = val;
        }
        for (int i = tid; i < OCT * 9; i += 256) {
            int oc = i / 9, t = i % 9;
            float wv = 0.f;
            if (ocBase + oc < OC) wv = w[((size_t)(ocBase + oc) * IC + ic) * 9 + t];
            s_w[i] = wv;
        }
        __syncthreads();

        float v[4][4];
#pragma unroll
        for (int r = 0; r < 4; ++r)
#pragma unroll
            for (int cc = 0; cc < 4; ++cc) v[r][cc] = s_in[(2 * ty + r) * 34 + (2 * tx + cc)];

#pragma unroll
        for (int oc = 0; oc < OCT; ++oc) {
#pragma unroll
            for (int ky = 0; ky < 3; ++ky)
#pragma unroll
                for (int kx = 0; kx < 3; ++kx) {
                    float wv = s_w[oc * 9 + ky * 3 + kx];
                    acc[oc][0] += wv * v[ky][kx];
                    acc[oc][1] += wv * v[ky][kx + 1];
                    acc[oc][2] += wv * v[ky + 1][kx];
                    acc[oc][3] += wv * v[ky + 1][kx + 1];
                }
        }
        __syncthreads();
    }

    int py = ty0 + 2 * ty, px = tx0 + 2 * tx;
#pragma unroll
    for (int oc = 0; oc < OCT; ++oc) {
        int og = ocBase + oc;
        if (og >= OC) continue;
        float bv = bias[og];
        size_t base = (((size_t)b * OC + og) * 64 + py) * 64 + px;
#pragma unroll
        for (int p = 0; p < 4; ++p) {
            int dy = p >> 1, dx = p & 1;
            size_t o = base + (size_t)dy * 64 + dx;
            out[o] = acc[oc][p] + bv;
        }
    }
}

// ---------------------------------------------------------------------------
// Skip conv: 5x5, pad=2, IC=3, OC=12, input offset -0.5
// ---------------------------------------------------------------------------
__global__ __launch_bounds__(256) void skip_conv_kernel(const float* __restrict__ x,
                                                        const float* __restrict__ w,
                                                        const float* __restrict__ bias,
                                                        float* __restrict__ out) {
    int idx = blockIdx.x * 256 + threadIdx.x;
    int px = idx & 63;
    int py = (idx >> 6) & 63;
    int v = idx >> 12;
    int oc = v % 12;
    int b = v / 12;
    float acc = bias[oc];
    for (int ic = 0; ic < 3; ++ic)
        for (int ky = 0; ky < 5; ++ky) {
            int gy = py + ky - 2;
            if (gy < 0 || gy >= 64) continue;
            for (int kx = 0; kx < 5; ++kx) {
                int gx = px + kx - 2;
                if (gx < 0 || gx >= 64) continue;
                acc += w[((oc * 3 + ic) * 5 + ky) * 5 + kx] *
                       (x[((size_t)(b * 3 + ic) * 64 + gy) * 64 + gx] - 0.5f);
            }
        }
    out[idx] = acc;
}

// ---------------------------------------------------------------------------
// Pixel shuffle (r=2) + skip add + IMAGE_MEAN
// ---------------------------------------------------------------------------
__global__ __launch_bounds__(256) void shuffle_kernel(const float* __restrict__ body,
                                                      const float* __restrict__ skipb,
                                                      float* __restrict__ out) {
    int idx = blockIdx.x * 256 + threadIdx.x;
    int ox = idx & 127;
    int oy = (idx >> 7) & 127;
    int v = idx >> 14;
    int c = v % 3;
    int b = v / 3;
    int rx = ox & 1, ry = oy & 1;
    int xx = ox >> 1, yy = oy >> 1;
    int ch = c * 4 + ry * 2 + rx;
    size_t src = (((size_t)b * 12 + ch) * 64 + yy) * 64 + xx;
    out[idx] = body[src] + skipb[src] + 0.5f;
}

// ---------------------------------------------------------------------------
extern "C" void kernel_launch(void* const* d_in, const int* in_sizes, int n_in,
                              void* d_out, int out_size, void* d_ws, size_t ws_size,
                              hipStream_t stream) {
    const float* x      = (const float*)d_in[0];
    const float* head_v = (const float*)d_in[1];
    const float* head_g = (const float*)d_in[2];
    const float* head_b = (const float*)d_in[3];
    const float* b1_v   = (const float*)d_in[4];
    const float* b1_g   = (const float*)d_in[5];
    const float* b1_b   = (const float*)d_in[6];
    const float* b1_mw  = (const float*)d_in[7];
    const float* b1_mb  = (const float*)d_in[8];
    const float* b2_v   = (const float*)d_in[9];
    const float* b2_g   = (const float*)d_in[10];
    const float* b2_b   = (const float*)d_in[11];
    const float* b2_mw  = (const float*)d_in[12];
    const float* b2_mb  = (const float*)d_in[13];
    const float* tail_v = (const float*)d_in[14];
    const float* tail_g = (const float*)d_in[15];
    const float* tail_b = (const float*)d_in[16];
    const float* skip_v = (const float*)d_in[17];
    const float* skip_g = (const float*)d_in[18];
    const float* skip_b = (const float*)d_in[19];

    float* ws = (float*)d_ws;
    size_t off = 0;
    auto alloc = [&](size_t n) { float* p = ws + off; off += n; return p; };
    float* head_w = alloc(64 * 27 + 4);
    float* b1_w   = alloc((size_t)2048 * 576);
    float* b2_w   = alloc((size_t)512 * 2304);
    float* tail_w = alloc(12 * 576 + 4);
    float* skip_w = alloc(12 * 75 + 4);
    float* h      = alloc((size_t)8 * 64 * 4096);
    float* t      = alloc((size_t)8 * 256 * 4096);
    float* meanb  = alloc(2048);
    float* sbuf   = alloc(64);
    unsigned short* wq1 = (unsigned short*)alloc((size_t)8 * 256 * 576 / 2);  // bf16
    float* bper1  = alloc(2048);
    unsigned short* wq2 = (unsigned short*)alloc((size_t)8 * 64 * 2304 / 2);  // bf16
    float* bper2  = alloc(512);
    float* body   = alloc((size_t)8 * 12 * 4096);
    float* skipb  = alloc((size_t)8 * 12 * 4096);
    (void)ws_size; (void)in_sizes; (void)n_in; (void)out_size;

    // Weight norms
    wn_kernel<<<64, 256, 0, stream>>>(head_v, head_g, head_w, 27);
    wn_kernel<<<2048, 256, 0, stream>>>(b1_v, b1_g, b1_w, 576);
    wn_kernel<<<512, 256, 0, stream>>>(b2_v, b2_g, b2_w, 2304);
    wn_kernel<<<12, 256, 0, stream>>>(tail_v, tail_g, tail_w, 576);
    wn_kernel<<<12, 256, 0, stream>>>(skip_v, skip_g, skip_w, 75);

    // Head: 3 -> 64 (direct fp32)
    conv3x3_direct<16><<<dim3(4, 4, 8), 256, 0, stream>>>(x, head_w, head_b, h, 3, 64, -0.5f);

    for (int l = 0; l < 4; ++l) {
        // dyn conv 1: 64 -> 256, relu
        mean_kernel<<<512, 256, 0, stream>>>(h, meanb);
        route_kernel<<<1, 64, 0, stream>>>(meanb, b1_mw + (size_t)l * 8 * 64,
                                           b1_mb + l * 8, sbuf, 64);
        combine_w_mfma<<<4608, 256, 0, stream>>>(b1_w + (size_t)l * 512 * 576, sbuf,
                                                 wq1, 64, 64, 256, 64);
        combine_b_kernel<<<8, 256, 0, stream>>>(b1_b + l * 512, sbuf, bper1, 64, 256);
        conv_mfma<64, 256, 64, 4, true, false>
            <<<dim3(16, 4, 8), 256, 0, stream>>>(h, wq1, bper1, nullptr, t);

        // dyn conv 2: 256 -> 64, + residual h (in place)
        mean_kernel<<<2048, 256, 0, stream>>>(t, meanb);
        route_kernel<<<1, 64, 0, stream>>>(meanb, b2_mw + (size_t)l * 8 * 256,
                                           b2_mb + l * 8, sbuf, 256);
        combine_w_mfma<<<4608, 256, 0, stream>>>(b2_w + (size_t)l * 128 * 2304, sbuf,
                                                 wq2, 16, 256, 64, 64);
        combine_b_kernel<<<2, 256, 0, stream>>>(b2_b + l * 128, sbuf, bper2, 16, 64);
        conv_mfma<256, 64, 64, 2, false, true>
            <<<dim3(32, 1, 8), 256, 0, stream>>>(t, wq2, bper2, h, h);
    }

    // Tail: 64 -> 12 (direct fp32)
    conv3x3_direct<4><<<dim3(4, 3, 8), 256, 0, stream>>>(h, tail_w, tail_b, body, 64, 12, 0.f);
    // Skip: 3 -> 12, 5x5
    skip_conv_kernel<<<1536, 256, 0, stream>>>(x, skip_w, skip_b, skipb);
    // Pixel shuffle + mean
    shuffle_kernel<<<1536, 256, 0, stream>>>(body, skipb, (float*)d_out);
}

// Round 3
// 651.281 us; speedup vs baseline: 5.7612x; 1.0642x over previous
//
#include <hip/hip_runtime.h>

typedef __attribute__((ext_vector_type(8))) short bf16x8;
typedef __attribute__((ext_vector_type(4))) float f32x4;
typedef __attribute__((ext_vector_type(4))) unsigned short u16x4;

__device__ __forceinline__ unsigned short bf16u(float x) {
    unsigned int u = __builtin_bit_cast(unsigned int, x);
    unsigned int r = (u + 0x7fffu + ((u >> 16) & 1u)) >> 16;
    return (unsigned short)r;
}
__device__ __forceinline__ float bf2f(unsigned short u) {
    return __builtin_bit_cast(float, (unsigned int)u << 16);
}
__device__ __forceinline__ void gll16(const void* g, void* l) {
    __builtin_amdgcn_global_load_lds((const __attribute__((address_space(1))) void*)g,
                                     (__attribute__((address_space(3))) void*)l, 16, 0, 0);
}

// ---------------------------------------------------------------------------
// Full weight norm (small tensors: head/tail/skip)
// ---------------------------------------------------------------------------
__global__ __launch_bounds__(256) void wn_kernel(const float* __restrict__ v,
                                                 const float* __restrict__ g,
                                                 float* __restrict__ out, int len) {
    __shared__ float red[4];
    __shared__ float s_scale;
    int row = blockIdx.x;
    const float* vr = v + (size_t)row * len;
    float ss = 0.f;
    for (int i = threadIdx.x; i < len; i += 256) { float a = vr[i]; ss += a * a; }
    for (int o = 32; o > 0; o >>= 1) ss += __shfl_down(ss, o);
    if ((threadIdx.x & 63) == 0) red[threadIdx.x >> 6] = ss;
    __syncthreads();
    if (threadIdx.x == 0) s_scale = g[row] / sqrtf(red[0] + red[1] + red[2] + red[3]);
    __syncthreads();
    float sc = s_scale;
    float* orow = out + (size_t)row * len;
    for (int i = threadIdx.x; i < len; i += 256) orow[i] = vr[i] * sc;
}

// Scale-only weight norm (big dyn weights): sc[row] = g/||v||
__global__ __launch_bounds__(256) void wn_scale(const float* __restrict__ v,
                                                const float* __restrict__ g,
                                                float* __restrict__ sc, int len) {
    __shared__ float red[4];
    int row = blockIdx.x;
    const float* vr = v + (size_t)row * len;
    float ss = 0.f;
    for (int i = threadIdx.x; i < len; i += 256) { float a = vr[i]; ss += a * a; }
    for (int o = 32; o > 0; o >>= 1) ss += __shfl_down(ss, o);
    if ((threadIdx.x & 63) == 0) red[threadIdx.x >> 6] = ss;
    __syncthreads();
    if (threadIdx.x == 0) sc[row] = g[row] / sqrtf(red[0] + red[1] + red[2] + red[3]);
}

// ---------------------------------------------------------------------------
// Per-(b,ch) spatial mean over 64x64 fp32 NCHW. grid.x = B*CH
// ---------------------------------------------------------------------------
__global__ __launch_bounds__(256) void mean_kernel(const float* __restrict__ in,
                                                   float* __restrict__ out) {
    __shared__ float red[4];
    int row = blockIdx.x;
    const float* p = in + (size_t)row * 4096;
    float s = 0.f;
    for (int i = threadIdx.x; i < 4096; i += 256) s += p[i];
    for (int o = 32; o > 0; o >>= 1) s += __shfl_down(s, o);
    if ((threadIdx.x & 63) == 0) red[threadIdx.x >> 6] = s;
    __syncthreads();
    if (threadIdx.x == 0) out[row] = (red[0] + red[1] + red[2] + red[3]) * (1.f / 4096.f);
}

__global__ void zero_f(float* p, int n) {
    int i = blockIdx.x * 256 + threadIdx.x;
    if (i < n) p[i] = 0.f;
}

// Mean from padded NHWC bf16 (IC=256). grid (8 slabs, 8 b), 256 thr = channels.
__global__ __launch_bounds__(256) void mean_nhwc(const unsigned short* __restrict__ tbf,
                                                 float* __restrict__ meanb) {
    int b = blockIdx.y, slab = blockIdx.x;
    int tid = threadIdx.x;
    float acc = 0.f;
    for (int p = 0; p < 512; ++p) {
        int y = slab * 8 + (p >> 6), x = p & 63;
        acc += bf2f(tbf[(((size_t)b * 66 + y + 1) * 66 + (x + 1)) * 256 + tid]);
    }
    atomicAdd(&meanb[b * 256 + tid], acc * (1.f / 4096.f));
}

// ---------------------------------------------------------------------------
// Routing softmax + per-sample bias combine. 1 block, 64 threads.
// ---------------------------------------------------------------------------
__global__ void route_cb(const float* __restrict__ mean, const float* __restrict__ mw,
                         const float* __restrict__ mb, const float* __restrict__ bias,
                         float* __restrict__ s_out, float* __restrict__ bper,
                         int IC, int OC, int D) {
    __shared__ float lg[64];
    __shared__ float sh[64];
    int tid = threadIdx.x;
    int b = tid >> 3, j = tid & 7;
    float acc = mb[j];
    for (int i = 0; i < IC; ++i) acc += mean[b * IC + i] * mw[j * IC + i];
    lg[tid] = acc;
    __syncthreads();
    int g = j >> 2, c = j & 3;
    float l0 = lg[b * 8 + c], l1 = lg[b * 8 + 4 + c];
    float m = fmaxf(l0, l1);
    float e0 = __expf(l0 - m), e1 = __expf(l1 - m);
    float v = ((g == 0) ? e0 : e1) / (e0 + e1);
    s_out[tid] = v;
    sh[tid] = v;
    __syncthreads();
    for (int i = tid; i < 8 * OC; i += 64) {
        int oc = i % OC, bb = i / OC, cc = oc / D;
        bper[i] = sh[bb * 8 + cc] * bias[oc] + sh[bb * 8 + 4 + cc] * bias[OC + oc];
    }
}

// ---------------------------------------------------------------------------
// Per-sample weight combine (wn fused): bf16 fragment order
// [b][ot][kc][tap][kg][mo][kj], oc = ot*MT+mo, ic = kc*32+kg*8+kj
// ---------------------------------------------------------------------------
__global__ __launch_bounds__(256) void combine_w2(const float* __restrict__ v,
                                                  const float* __restrict__ scale,
                                                  const float* __restrict__ s,
                                                  unsigned short* __restrict__ wq,
                                                  int D, int IC, int OC, int MT) {
    int idx = blockIdx.x * 256 + threadIdx.x;  // exact grid: 8*OC*IC*9
    int kj = idx & 7;
    int tmp = idx >> 3;
    int mo = tmp % MT; tmp /= MT;
    int kg = tmp & 3; tmp >>= 2;
    int t = tmp % 9; tmp /= 9;
    int KCh = IC >> 5;
    int kc = tmp % KCh; tmp /= KCh;
    int OT = OC / MT;
    int ot = tmp % OT;
    int b = tmp / OT;
    int oc = ot * MT + mo;
    int ic = kc * 32 + kg * 8 + kj;
    int c = oc / D;
    float s0 = s[b * 8 + c], s1 = s[b * 8 + 4 + c];
    float val = s0 * scale[oc] * v[((size_t)oc * IC + ic) * 9 + t] +
                s1 * scale[OC + oc] * v[((size_t)(OC + oc) * IC + ic) * 9 + t];
    wq[idx] = bf16u(val);
}

// Static tail weight repack: [kc=2][tap][kg][mo=16][kj], zeros for mo>=12
__global__ void tail_repack(const float* __restrict__ tw, unsigned short* __restrict__ wq) {
    int idx = blockIdx.x * 256 + threadIdx.x;  // 9216
    int kj = idx & 7;
    int tmp = idx >> 3;
    int mo = tmp % 16; tmp /= 16;
    int kg = tmp & 3; tmp >>= 2;
    int t = tmp % 9; tmp /= 9;
    int kc = tmp;
    int ic = kc * 32 + kg * 8 + kj;
    float val = (mo < 12) ? tw[((size_t)mo * 64 + ic) * 9 + t] : 0.f;
    wq[idx] = bf16u(val);
}

// Zero the spatial border of a padded NHWC buffer [8][66][66][IC]
__global__ __launch_bounds__(256) void zero_border(unsigned short* __restrict__ buf, int IC) {
    int idx = blockIdx.x * 256 + threadIdx.x;
    int total = 8 * 260 * IC;
    if (idx >= total) return;
    int ic = idx % IC;
    int r = (idx / IC) % 260;
    int b = idx / (IC * 260);
    int y, x;
    if (r < 66) { y = 0; x = r; }
    else if (r < 132) { y = 65; x = r - 66; }
    else if (r < 196) { y = r - 131; x = 0; }
    else { y = r - 195; x = 65; }
    buf[(((size_t)b * 66 + y) * 66 + x) * IC + ic] = 0;
}

// ---------------------------------------------------------------------------
// MFMA implicit-GEMM 3x3 conv. Input: padded NHWC bf16 [8][66][66][IC].
// Weights: fragment-ordered bf16. 4 waves = WM x WN grid.
// LDS input tile staged via global_load_lds with slot-involution swizzle
// s^((s>>3)&7) applied on the SOURCE address (LDS dest linear).
// ---------------------------------------------------------------------------
template <int IC, int OC, int MT, int WM, int WN, int NR,
          bool RELU, bool RES, bool WF32, bool WBF, int OCR>
__global__ __launch_bounds__(256) void conv_mfma(
    const unsigned short* __restrict__ in_bf,
    const unsigned short* __restrict__ wq,
    const float* __restrict__ bias, int bstride,
    const float* __restrict__ res,
    float* __restrict__ out,
    unsigned short* __restrict__ out_bf,
    long wstride) {
    constexpr int KCH = IC / 32;
    constexpr int NRH = NR + 2;
    constexpr int NT = NR * 64;
    constexpr int NFT = NT / 16;
    constexpr int NF = NFT / WN;
    constexpr int MW = MT / (16 * WM);
    constexpr int WELEM = 9 * 32 * MT;      // bf16 elems per kc chunk
    constexpr int SCH = NRH * 66 * 4;       // 16B chunks of S
    constexpr int WCH = WELEM / 8;          // 16B chunks of W

    __shared__ __align__(16) unsigned short S[NRH * 66 * 32];
    __shared__ __align__(16) unsigned short W[WELEM];

    const int b = blockIdx.z, ot = blockIdx.y;
    const int y0 = blockIdx.x * NR;
    const int tid = threadIdx.x;
    const int lane = tid & 63, wid = tid >> 6;
    const int wm = wid / WN, wn = wid % WN;
    const int l15 = lane & 15, lk = lane >> 4;
    const int wmo = wm * (MT / WM);
    const int wno = wn * (NT / WN);

    f32x4 acc[MW][NF];
#pragma unroll
    for (int mf = 0; mf < MW; ++mf)
#pragma unroll
        for (int nf = 0; nf < NF; ++nf)
#pragma unroll
            for (int q = 0; q < 4; ++q) acc[mf][nf][q] = 0.f;

    const unsigned short* inb = in_bf + (size_t)b * 66 * 66 * IC;
    const unsigned short* wqb = wq + (size_t)b * wstride + (size_t)ot * (KCH * WELEM);

    for (int kc = 0; kc < KCH; ++kc) {
        __syncthreads();
        // stage weights (linear)
        const unsigned short* wsrc = wqb + kc * WELEM;
        for (int cb = wid; cb * 64 < WCH; cb += 4) {
            int p = cb * 64 + lane;
            if (p < WCH) gll16(wsrc + p * 8, (char*)W + p * 16);
        }
        // stage input tile (swizzled source, linear dest)
        const int icb = kc * 32;
        for (int cb = wid; cb * 64 < SCH; cb += 4) {
            int p = cb * 64 + lane;
            if (p < SCH) {
                int Lz = p ^ ((p >> 3) & 7);
                int lk2 = Lz & 3;
                int cr = Lz >> 2;
                int col = cr % 66, row = cr / 66;
                const unsigned short* src =
                    inb + ((size_t)(y0 + row) * 66 + col) * IC + icb + lk2 * 8;
                gll16(src, (char*)S + p * 16);
            }
        }
        __syncthreads();
#pragma unroll
        for (int t = 0; t < 9; ++t) {
            const int dy = t / 3, dx = t % 3;
            bf16x8 a[MW];
#pragma unroll
            for (int mf = 0; mf < MW; ++mf)
                a[mf] = *(const bf16x8*)&W[((t * 4 + lk) * MT + wmo + mf * 16 + l15) * 8];
#pragma unroll
            for (int nf = 0; nf < NF; ++nf) {
                int n = wno + nf * 16 + l15;
                int r = n >> 6, c = n & 63;
                int L = ((r + dy) * 66 + (c + dx)) * 4 + lk;
                int P = L ^ ((L >> 3) & 7);
                bf16x8 bv = *(const bf16x8*)((const char*)S + P * 16);
#pragma unroll
                for (int mf = 0; mf < MW; ++mf)
                    acc[mf][nf] = __builtin_amdgcn_mfma_f32_16x16x32_bf16(a[mf], bv, acc[mf][nf], 0, 0, 0);
            }
        }
    }
    // epilogue: C/D map col=lane&15, row=(lane>>4)*4+q
#pragma unroll
    for (int mf = 0; mf < MW; ++mf) {
        int ocb = ot * MT + wmo + mf * 16 + lk * 4;
#pragma unroll
        for (int nf = 0; nf < NF; ++nf) {
            int n = wno + nf * 16 + l15;
            int y = y0 + (n >> 6), x = n & 63;
            float vv[4];
#pragma unroll
            for (int q = 0; q < 4; ++q) {
                int oc = ocb + q;
                float v = 0.f;
                if (oc < OCR) {
                    v = acc[mf][nf][q] + bias[bstride * b + oc];
                    if (RELU) v = fmaxf(v, 0.f);
                    size_t o = (((size_t)b * OCR + oc) * 64 + y) * 64 + x;
                    if (RES) v += res[o];
                    if (WF32) out[o] = v;
                }
                vv[q] = v;
            }
            if (WBF) {
                u16x4 pk;
#pragma unroll
                for (int q = 0; q < 4; ++q) pk[q] = bf16u(vv[q]);
                if (ocb < OCR)
                    *(u16x4*)&out_bf[(((size_t)b * 66 + y + 1) * 66 + (x + 1)) * OCR + ocb] = pk;
            }
        }
    }
}

// ---------------------------------------------------------------------------
// Direct 3x3 conv for head (IC=3), writes fp32 NCHW + bf16 padded NHWC
// ---------------------------------------------------------------------------
__global__ __launch_bounds__(256) void head_conv(
    const float* __restrict__ in, const float* __restrict__ w,
    const float* __restrict__ bias, float* __restrict__ out,
    unsigned short* __restrict__ out_bf) {
    constexpr int OCT = 16, IC = 3;
    __shared__ float s_in[34 * 34];
    __shared__ float s_w[OCT * 9];
    int b = blockIdx.z;
    int ocBase = blockIdx.y * OCT;
    int ty0 = (blockIdx.x >> 1) * 32;
    int tx0 = (blockIdx.x & 1) * 32;
    int tid = threadIdx.x;
    int tx = tid & 15, ty = tid >> 4;

    float acc[OCT][4];
#pragma unroll
    for (int oc = 0; oc < OCT; ++oc)
#pragma unroll
        for (int p = 0; p < 4; ++p) acc[oc][p] = 0.f;

    const float* inb = in + (size_t)b * IC * 4096;
    for (int ic = 0; ic < IC; ++ic) {
        const float* src = inb + (size_t)ic * 4096;
        for (int i = tid; i < 34 * 34; i += 256) {
            int r = i / 34, cc = i % 34;
            int gy = ty0 + r - 1, gx = tx0 + cc - 1;
            float val = 0.f;
            if (gy >= 0 && gy < 64 && gx >= 0 && gx < 64) val = src[gy * 64 + gx] - 0.5f;
            s_in[i] = val;
        }
        for (int i = tid; i < OCT * 9; i += 256) {
            int oc = i / 9, t = i % 9;
            s_w[i] = w[((size_t)(ocBase + oc) * IC + ic) * 9 + t];
        }
        __syncthreads();
        float v[4][4];
#pragma unroll
        for (int r = 0; r < 4; ++r)
#pragma unroll
            for (int cc = 0; cc < 4; ++cc) v[r][cc] = s_in[(2 * ty + r) * 34 + (2 * tx + cc)];
#pragma unroll
        for (int oc = 0; oc < OCT; ++oc) {
#pragma unroll
            for (int ky = 0; ky < 3; ++ky)
#pragma unroll
                for (int kx = 0; kx < 3; ++kx) {
                    float wv = s_w[oc * 9 + ky * 3 + kx];
                    acc[oc][0] += wv * v[ky][kx];
                    acc[oc][1] += wv * v[ky][kx + 1];
                    acc[oc][2] += wv * v[ky + 1][kx];
                    acc[oc][3] += wv * v[ky + 1][kx + 1];
                }
        }
        __syncthreads();
    }
    int py = ty0 + 2 * ty, px = tx0 + 2 * tx;
#pragma unroll
    for (int oc = 0; oc < OCT; ++oc) {
        int og = ocBase + oc;
        float bv = bias[og];
#pragma unroll
        for (int p = 0; p < 4; ++p) {
            int dy = p >> 1, dx = p & 1;
            float val = acc[oc][p] + bv;
            out[(((size_t)b * 64 + og) * 64 + py + dy) * 64 + px + dx] = val;
            out_bf[(((size_t)b * 66 + py + dy + 1) * 66 + (px + dx + 1)) * 64 + og] = bf16u(val);
        }
    }
}

// ---------------------------------------------------------------------------
// Skip conv 5x5, pad=2, IC=3, OC=12
// ---------------------------------------------------------------------------
__global__ __launch_bounds__(256) void skip_conv_kernel(const float* __restrict__ x,
                                                        const float* __restrict__ w,
                                                        const float* __restrict__ bias,
                                                        float* __restrict__ out) {
    int idx = blockIdx.x * 256 + threadIdx.x;
    int px = idx & 63;
    int py = (idx >> 6) & 63;
    int v = idx >> 12;
    int oc = v % 12;
    int b = v / 12;
    float acc = bias[oc];
    for (int ic = 0; ic < 3; ++ic)
        for (int ky = 0; ky < 5; ++ky) {
            int gy = py + ky - 2;
            if (gy < 0 || gy >= 64) continue;
            for (int kx = 0; kx < 5; ++kx) {
                int gx = px + kx - 2;
                if (gx < 0 || gx >= 64) continue;
                acc += w[((oc * 3 + ic) * 5 + ky) * 5 + kx] *
                       (x[((size_t)(b * 3 + ic) * 64 + gy) * 64 + gx] - 0.5f);
            }
        }
    out[idx] = acc;
}

// ---------------------------------------------------------------------------
// Pixel shuffle (r=2) + skip add + IMAGE_MEAN
// ---------------------------------------------------------------------------
__global__ __launch_bounds__(256) void shuffle_kernel(const float* __restrict__ body,
                                                      const float* __restrict__ skipb,
                                                      float* __restrict__ out) {
    int idx = blockIdx.x * 256 + threadIdx.x;
    int ox = idx & 127;
    int oy = (idx >> 7) & 127;
    int v = idx >> 14;
    int c = v % 3;
    int b = v / 3;
    int rx = ox & 1, ry = oy & 1;
    int xx = ox >> 1, yy = oy >> 1;
    int ch = c * 4 + ry * 2 + rx;
    size_t src = (((size_t)b * 12 + ch) * 64 + yy) * 64 + xx;
    out[idx] = body[src] + skipb[src] + 0.5f;
}

// ---------------------------------------------------------------------------
extern "C" void kernel_launch(void* const* d_in, const int* in_sizes, int n_in,
                              void* d_out, int out_size, void* d_ws, size_t ws_size,
                              hipStream_t stream) {
    const float* x      = (const float*)d_in[0];
    const float* head_v = (const float*)d_in[1];
    const float* head_g = (const float*)d_in[2];
    const float* head_b = (const float*)d_in[3];
    const float* b1_v   = (const float*)d_in[4];
    const float* b1_g   = (const float*)d_in[5];
    const float* b1_b   = (const float*)d_in[6];
    const float* b1_mw  = (const float*)d_in[7];
    const float* b1_mb  = (const float*)d_in[8];
    const float* b2_v   = (const float*)d_in[9];
    const float* b2_g   = (const float*)d_in[10];
    const float* b2_b   = (const float*)d_in[11];
    const float* b2_mw  = (const float*)d_in[12];
    const float* b2_mb  = (const float*)d_in[13];
    const float* tail_v = (const float*)d_in[14];
    const float* tail_g = (const float*)d_in[15];
    const float* tail_b = (const float*)d_in[16];
    const float* skip_v = (const float*)d_in[17];
    const float* skip_g = (const float*)d_in[18];
    const float* skip_b = (const float*)d_in[19];

    float* ws = (float*)d_ws;
    size_t off = 0;
    auto alloc = [&](size_t n) { float* p = ws + off; off += (n + 3) & ~(size_t)3; return p; };
    float* head_w = alloc(64 * 27);
    float* tail_w = alloc(12 * 576);
    float* skip_w = alloc(12 * 75);
    float* b1_sc  = alloc(2048);
    float* b2_sc  = alloc(512);
    float* h      = alloc((size_t)8 * 64 * 4096);
    float* meanb  = alloc(2048);
    float* sbuf   = alloc(64);
    float* bper1  = alloc(2048);
    float* bper2  = alloc(512);
    float* body   = alloc((size_t)8 * 12 * 4096);
    float* skipb  = alloc((size_t)8 * 12 * 4096);
    unsigned short* wq1  = (unsigned short*)alloc((size_t)8 * 256 * 576 / 2);
    unsigned short* wq2  = (unsigned short*)alloc((size_t)8 * 64 * 2304 / 2);
    unsigned short* wqt  = (unsigned short*)alloc(9216 / 2);
    unsigned short* h_bf = (unsigned short*)alloc((size_t)8 * 66 * 66 * 64 / 2);
    unsigned short* t_bf = (unsigned short*)alloc((size_t)8 * 66 * 66 * 256 / 2);
    (void)ws_size; (void)in_sizes; (void)n_in; (void)out_size;

    // weight norms
    wn_kernel<<<64, 256, 0, stream>>>(head_v, head_g, head_w, 27);
    wn_kernel<<<12, 256, 0, stream>>>(tail_v, tail_g, tail_w, 576);
    wn_kernel<<<12, 256, 0, stream>>>(skip_v, skip_g, skip_w, 75);
    wn_scale<<<2048, 256, 0, stream>>>(b1_v, b1_g, b1_sc, 576);
    wn_scale<<<512, 256, 0, stream>>>(b2_v, b2_g, b2_sc, 2304);

    // zero NHWC borders
    zero_border<<<520, 256, 0, stream>>>(h_bf, 64);
    zero_border<<<2080, 256, 0, stream>>>(t_bf, 256);

    // head + tail weight repack
    head_conv<<<dim3(4, 4, 8), 256, 0, stream>>>(x, head_w, head_b, h, h_bf);
    tail_repack<<<36, 256, 0, stream>>>(tail_w, wqt);

    for (int l = 0; l < 4; ++l) {
        // --- dyn conv 1: 64 -> 256, relu, writes t_bf only ---
        mean_kernel<<<512, 256, 0, stream>>>(h, meanb);
        route_cb<<<1, 64, 0, stream>>>(meanb, b1_mw + (size_t)l * 8 * 64, b1_mb + l * 8,
                                       b1_b + (size_t)l * 512, sbuf, bper1, 64, 256, 64);
        combine_w2<<<4608, 256, 0, stream>>>(b1_v + (size_t)l * 512 * 576,
                                             b1_sc + (size_t)l * 512, sbuf, wq1, 64, 64, 256, 64);
        conv_mfma<64, 256, 64, 2, 2, 4, true, false, false, true, 256>
            <<<dim3(16, 4, 8), 256, 0, stream>>>(h_bf, wq1, bper1, 256, nullptr,
                                                 nullptr, t_bf, 147456);
        // --- dyn conv 2: 256 -> 64, +residual h, writes h and h_bf ---
        zero_f<<<8, 256, 0, stream>>>(meanb, 2048);
        mean_nhwc<<<dim3(8, 8), 256, 0, stream>>>(t_bf, meanb);
        route_cb<<<1, 64, 0, stream>>>(meanb, b2_mw + (size_t)l * 8 * 256, b2_mb + l * 8,
                                       b2_b + (size_t)l * 128, sbuf, bper2, 256, 64, 16);
        combine_w2<<<4608, 256, 0, stream>>>(b2_v + (size_t)l * 128 * 2304,
                                             b2_sc + (size_t)l * 128, sbuf, wq2, 16, 256, 64, 32);
        conv_mfma<256, 64, 32, 2, 2, 2, false, true, true, true, 64>
            <<<dim3(32, 2, 8), 256, 0, stream>>>(t_bf, wq2, bper2, 64, h, h, h_bf, 147456);
    }

    // tail: 64 -> 12 via MFMA (padded to 16)
    conv_mfma<64, 16, 16, 1, 4, 4, false, false, true, false, 12>
        <<<dim3(16, 1, 8), 256, 0, stream>>>(h_bf, wqt, tail_b, 0, nullptr, body, nullptr, 0);
    // skip: 3 -> 12, 5x5
    skip_conv_kernel<<<1536, 256, 0, stream>>>(x, skip_w, skip_b, skipb);
    // pixel shuffle + mean
    shuffle_kernel<<<1536, 256, 0, stream>>>(body, skipb, (float*)d_out);
}

// Round 4
// 351.083 us; speedup vs baseline: 10.6875x; 1.8551x over previous
//
#include <hip/hip_runtime.h>

typedef __attribute__((ext_vector_type(8))) short bf16x8;
typedef __attribute__((ext_vector_type(4))) float f32x4;
typedef __attribute__((ext_vector_type(4))) unsigned short u16x4;
typedef __attribute__((ext_vector_type(8))) unsigned short u16x8;

__device__ __forceinline__ unsigned short bf16u(float x) {
    unsigned int u = __builtin_bit_cast(unsigned int, x);
    unsigned int r = (u + 0x7fffu + ((u >> 16) & 1u)) >> 16;
    return (unsigned short)r;
}
__device__ __forceinline__ void gll16(const void* g, void* l) {
    __builtin_amdgcn_global_load_lds((const __attribute__((address_space(1))) void*)g,
                                     (__attribute__((address_space(3))) void*)l, 16, 0, 0);
}

// ---------------------------------------------------------------------------
// One-shot zeroing: h_bf border, t_bf border, mean-sum buffers. grid 335x256.
// ---------------------------------------------------------------------------
__global__ __launch_bounds__(256) void zero_all(unsigned short* __restrict__ hbf,
                                                unsigned short* __restrict__ tbf,
                                                float* __restrict__ sums) {
    int i = blockIdx.x * 256 + threadIdx.x;
    u16x8 z8 = {0, 0, 0, 0, 0, 0, 0, 0};
    if (i < 16640) {
        int chv = i & 7, pb = i >> 3, pos = pb % 260, b = pb / 260;
        int y, x;
        if (pos < 66) { y = 0; x = pos; }
        else if (pos < 132) { y = 65; x = pos - 66; }
        else if (pos < 196) { y = pos - 131; x = 0; }
        else { y = pos - 195; x = 65; }
        *(u16x8*)&hbf[(((size_t)b * 66 + y) * 66 + x) * 64 + chv * 8] = z8;
    } else if (i < 83200) {
        int j = i - 16640;
        int chv = j & 31, pb = j >> 5, pos = pb % 260, b = pb / 260;
        int y, x;
        if (pos < 66) { y = 0; x = pos; }
        else if (pos < 132) { y = 65; x = pos - 66; }
        else if (pos < 196) { y = pos - 131; x = 0; }
        else { y = pos - 195; x = 65; }
        *(u16x8*)&tbf[(((size_t)b * 66 + y) * 66 + x) * 256 + chv * 8] = z8;
    } else {
        int k = i - 83200;  // < 2560
        f32x4 z4 = {0.f, 0.f, 0.f, 0.f};
        ((f32x4*)sums)[k] = z4;
    }
}

// ---------------------------------------------------------------------------
// All weight norms in one launch. Blocks: [0,64) head full, [64,76) tail full,
// [76,88) skip full, [88,2136) b1 scale-only, [2136,2648) b2 scale-only.
// ---------------------------------------------------------------------------
__global__ __launch_bounds__(256) void wn_all(
    const float* __restrict__ hv, const float* __restrict__ hg, float* __restrict__ hw,
    const float* __restrict__ tv, const float* __restrict__ tg, float* __restrict__ tw,
    const float* __restrict__ kv, const float* __restrict__ kg, float* __restrict__ kw,
    const float* __restrict__ b1v, const float* __restrict__ b1g, float* __restrict__ b1s,
    const float* __restrict__ b2v, const float* __restrict__ b2g, float* __restrict__ b2s) {
    int blk = blockIdx.x;
    const float *v, *g;
    float *outw = nullptr, *outs = nullptr;
    int len, row;
    if (blk < 64)        { v = hv;  g = hg;  outw = hw;  len = 27;   row = blk; }
    else if (blk < 76)   { v = tv;  g = tg;  outw = tw;  len = 576;  row = blk - 64; }
    else if (blk < 88)   { v = kv;  g = kg;  outw = kw;  len = 75;   row = blk - 76; }
    else if (blk < 2136) { v = b1v; g = b1g; outs = b1s; len = 576;  row = blk - 88; }
    else                 { v = b2v; g = b2g; outs = b2s; len = 2304; row = blk - 2136; }

    __shared__ float red[4];
    __shared__ float s_sc;
    const float* vr = v + (size_t)row * len;
    float ss = 0.f;
    for (int i = threadIdx.x; i < len; i += 256) { float a = vr[i]; ss += a * a; }
    for (int o = 32; o > 0; o >>= 1) ss += __shfl_down(ss, o);
    if ((threadIdx.x & 63) == 0) red[threadIdx.x >> 6] = ss;
    __syncthreads();
    if (threadIdx.x == 0) s_sc = g[row] / sqrtf(red[0] + red[1] + red[2] + red[3]);
    __syncthreads();
    float sc = s_sc;
    if (outs) {
        if (threadIdx.x == 0) outs[row] = sc;
    } else {
        float* orow = outw + (size_t)row * len;
        for (int i = threadIdx.x; i < len; i += 256) orow[i] = vr[i] * sc;
    }
}

// ---------------------------------------------------------------------------
// Per-sample weight combine + in-block routing softmax (from raw pixel sums).
// wq layout [b][ot][kc][tap][kg][mo][kj]; exact grid 8*OC*IC*9/256.
// ---------------------------------------------------------------------------
__global__ __launch_bounds__(256) void combine_w2(
    const float* __restrict__ v, const float* __restrict__ scale,
    const float* __restrict__ msum, const float* __restrict__ mw,
    const float* __restrict__ mb, float* __restrict__ s_out,
    unsigned short* __restrict__ wq, int D, int IC, int OC, int MT, int icr) {
    __shared__ float lg[8];
    __shared__ float sv8[8];
    int tid = threadIdx.x;
    int bpb = (OC * IC * 9) >> 8;  // blocks per sample
    int b = blockIdx.x / bpb;
    {
        int j = tid >> 5, l32 = tid & 31;
        float part = 0.f;
        for (int i = l32; i < icr; i += 32) part += msum[b * icr + i] * mw[j * icr + i];
        for (int m = 16; m > 0; m >>= 1) part += __shfl_xor(part, m);
        if (l32 == 0) lg[j] = part * (1.f / 4096.f) + mb[j];
    }
    __syncthreads();
    if (tid < 8) {
        int g = tid >> 2, c = tid & 3;
        float l0 = lg[c], l1 = lg[4 + c];
        float m = fmaxf(l0, l1);
        float e0 = __expf(l0 - m), e1 = __expf(l1 - m);
        float val = ((g == 0) ? e0 : e1) / (e0 + e1);
        sv8[tid] = val;
        if (blockIdx.x == b * bpb) s_out[b * 8 + tid] = val;
    }
    __syncthreads();

    int idx = blockIdx.x * 256 + tid;
    int kj = idx & 7;
    int tmp = idx >> 3;
    int mo = tmp % MT; tmp /= MT;
    int kg = tmp & 3; tmp >>= 2;
    int t = tmp % 9; tmp /= 9;
    int KCh = IC >> 5;
    int kc = tmp % KCh; tmp /= KCh;
    int OT = OC / MT;
    int ot = tmp % OT;
    int oc = ot * MT + mo;
    int ic = kc * 32 + kg * 8 + kj;
    int c = oc / D;
    float s0 = sv8[c], s1 = sv8[4 + c];
    float val = s0 * scale[oc] * v[((size_t)oc * IC + ic) * 9 + t] +
                s1 * scale[OC + oc] * v[((size_t)(OC + oc) * IC + ic) * 9 + t];
    wq[idx] = bf16u(val);
}

// Static tail weight repack: [kc=2][tap][kg][mo=16][kj], zeros for mo>=12
__global__ void tail_repack(const float* __restrict__ tw, unsigned short* __restrict__ wq) {
    int idx = blockIdx.x * 256 + threadIdx.x;  // 9216
    int kj = idx & 7;
    int tmp = idx >> 3;
    int mo = tmp % 16; tmp /= 16;
    int kg = tmp & 3; tmp >>= 2;
    int t = tmp % 9; tmp /= 9;
    int kc = tmp;
    int ic = kc * 32 + kg * 8 + kj;
    float val = (mo < 12) ? tw[((size_t)mo * 64 + ic) * 9 + t] : 0.f;
    wq[idx] = bf16u(val);
}

// ---------------------------------------------------------------------------
// MFMA implicit-GEMM 3x3 conv, padded NHWC bf16 input, fused mean-sum + bias.
// ---------------------------------------------------------------------------
template <int IC, int OC, int MT, int WM, int WN, int NR,
          bool RELU, bool RES, bool WF32, bool WBF, int OCR, bool DYNB>
__global__ __launch_bounds__(256) void conv_mfma(
    const unsigned short* __restrict__ in_bf,
    const unsigned short* __restrict__ wq,
    const float* __restrict__ bias_raw, const float* __restrict__ s8, int lgD,
    const float* __restrict__ res, float* __restrict__ out,
    unsigned short* __restrict__ out_bf, float* __restrict__ msum, long wstride) {
    constexpr int KCH = IC / 32;
    constexpr int NRH = NR + 2;
    constexpr int NT = NR * 64;
    constexpr int NF = (NT / 16) / WN;
    constexpr int MW = MT / (16 * WM);
    constexpr int WELEM = 9 * 32 * MT;
    constexpr int SCH = NRH * 66 * 4;
    constexpr int WCH = WELEM / 8;

    __shared__ __align__(16) unsigned short S[NRH * 66 * 32];
    __shared__ __align__(16) unsigned short W[WELEM];
    __shared__ float MRED[WN][MT];

    const int b = blockIdx.z, ot = blockIdx.y;
    const int y0 = blockIdx.x * NR;
    const int tid = threadIdx.x;
    const int lane = tid & 63, wid = tid >> 6;
    const int wm = wid / WN, wn = wid % WN;
    const int l15 = lane & 15, lk = lane >> 4;
    const int wmo = wm * (MT / WM);
    const int wno = wn * (NT / WN);

    f32x4 acc[MW][NF];
#pragma unroll
    for (int mf = 0; mf < MW; ++mf)
#pragma unroll
        for (int nf = 0; nf < NF; ++nf)
#pragma unroll
            for (int q = 0; q < 4; ++q) acc[mf][nf][q] = 0.f;

    const unsigned short* inb = in_bf + (size_t)b * 66 * 66 * IC;
    const unsigned short* wqb = wq + (size_t)b * wstride + (size_t)ot * (KCH * WELEM);

    for (int kc = 0; kc < KCH; ++kc) {
        __syncthreads();
        const unsigned short* wsrc = wqb + kc * WELEM;
        for (int cb = wid; cb * 64 < WCH; cb += 4) {
            int p = cb * 64 + lane;
            if (p < WCH) gll16(wsrc + p * 8, (char*)W + p * 16);
        }
        const int icb = kc * 32;
        for (int cb = wid; cb * 64 < SCH; cb += 4) {
            int p = cb * 64 + lane;
            if (p < SCH) {
                int Lz = p ^ ((p >> 3) & 7);
                int lk2 = Lz & 3;
                int cr = Lz >> 2;
                int col = cr % 66, row = cr / 66;
                const unsigned short* src =
                    inb + ((size_t)(y0 + row) * 66 + col) * IC + icb + lk2 * 8;
                gll16(src, (char*)S + p * 16);
            }
        }
        __syncthreads();
#pragma unroll
        for (int t = 0; t < 9; ++t) {
            const int dy = t / 3, dx = t % 3;
            bf16x8 a[MW];
#pragma unroll
            for (int mf = 0; mf < MW; ++mf)
                a[mf] = *(const bf16x8*)&W[((t * 4 + lk) * MT + wmo + mf * 16 + l15) * 8];
#pragma unroll
            for (int nf = 0; nf < NF; ++nf) {
                int n = wno + nf * 16 + l15;
                int r = n >> 6, c = n & 63;
                int L = ((r + dy) * 66 + (c + dx)) * 4 + lk;
                int P = L ^ ((L >> 3) & 7);
                bf16x8 bv = *(const bf16x8*)((const char*)S + P * 16);
#pragma unroll
                for (int mf = 0; mf < MW; ++mf)
                    acc[mf][nf] = __builtin_amdgcn_mfma_f32_16x16x32_bf16(a[mf], bv, acc[mf][nf], 0, 0, 0);
            }
        }
    }

    // epilogue: C/D map col=lane&15, row=(lane>>4)*4+q
    float msr[MW][4];
#pragma unroll
    for (int mf = 0; mf < MW; ++mf) {
        int ocb = ot * MT + wmo + mf * 16 + lk * 4;
        float bv[4];
#pragma unroll
        for (int q = 0; q < 4; ++q) {
            int oc = ocb + q;
            bv[q] = 0.f;
            if (oc < OCR) {
                if (DYNB) {
                    int c = oc >> lgD;
                    bv[q] = s8[b * 8 + c] * bias_raw[oc] + s8[b * 8 + 4 + c] * bias_raw[OCR + oc];
                } else {
                    bv[q] = bias_raw[oc];
                }
            }
            msr[mf][q] = 0.f;
        }
#pragma unroll
        for (int nf = 0; nf < NF; ++nf) {
            int n = wno + nf * 16 + l15;
            int y = y0 + (n >> 6), x = n & 63;
            float vv[4];
#pragma unroll
            for (int q = 0; q < 4; ++q) {
                int oc = ocb + q;
                float v = 0.f;
                if (oc < OCR) {
                    v = acc[mf][nf][q] + bv[q];
                    if (RELU) v = fmaxf(v, 0.f);
                    size_t o = (((size_t)b * OCR + oc) * 64 + y) * 64 + x;
                    if (RES) v += res[o];
                    if (WF32) out[o] = v;
                    msr[mf][q] += v;
                }
                vv[q] = v;
            }
            if (WBF) {
                u16x4 pk;
#pragma unroll
                for (int q = 0; q < 4; ++q) pk[q] = bf16u(vv[q]);
                if (ocb < OCR)
                    *(u16x4*)&out_bf[(((size_t)b * 66 + y + 1) * 66 + (x + 1)) * OCR + ocb] = pk;
            }
        }
    }
    if (msum) {
#pragma unroll
        for (int mf = 0; mf < MW; ++mf)
#pragma unroll
            for (int q = 0; q < 4; ++q) {
                float vq = msr[mf][q];
                vq += __shfl_xor(vq, 1);
                vq += __shfl_xor(vq, 2);
                vq += __shfl_xor(vq, 4);
                vq += __shfl_xor(vq, 8);
                if (l15 == 0) MRED[wn][wmo + mf * 16 + lk * 4 + q] = vq;
            }
        __syncthreads();
        if (tid < MT) {
            float tot = 0.f;
#pragma unroll
            for (int w2 = 0; w2 < WN; ++w2) tot += MRED[w2][tid];
            atomicAdd(&msum[b * OCR + ot * MT + tid], tot);
        }
    }
}

// ---------------------------------------------------------------------------
// Head conv 3->64 direct fp32; writes h (NCHW fp32), h_bf (padded NHWC bf16),
// and mean-sum partials for layer-0 routing.
// ---------------------------------------------------------------------------
__global__ __launch_bounds__(256) void head_conv(
    const float* __restrict__ in, const float* __restrict__ w,
    const float* __restrict__ bias, float* __restrict__ out,
    unsigned short* __restrict__ out_bf, float* __restrict__ hsum0) {
    constexpr int OCT = 16, IC = 3;
    __shared__ float s_in[34 * 34];
    __shared__ float s_w[OCT * 9];
    __shared__ float wred[4][OCT];
    int b = blockIdx.z;
    int ocBase = blockIdx.y * OCT;
    int ty0 = (blockIdx.x >> 1) * 32;
    int tx0 = (blockIdx.x & 1) * 32;
    int tid = threadIdx.x;
    int lane = tid & 63, wid = tid >> 6;
    int tx = tid & 15, ty = tid >> 4;

    float acc[OCT][4];
#pragma unroll
    for (int oc = 0; oc < OCT; ++oc)
#pragma unroll
        for (int p = 0; p < 4; ++p) acc[oc][p] = 0.f;

    const float* inb = in + (size_t)b * IC * 4096;
    for (int ic = 0; ic < IC; ++ic) {
        const float* src = inb + (size_t)ic * 4096;
        for (int i = tid; i < 34 * 34; i += 256) {
            int r = i / 34, cc = i % 34;
            int gy = ty0 + r - 1, gx = tx0 + cc - 1;
            float val = 0.f;
            if (gy >= 0 && gy < 64 && gx >= 0 && gx < 64) val = src[gy * 64 + gx] - 0.5f;
            s_in[i] = val;
        }
        for (int i = tid; i < OCT * 9; i += 256) {
            int oc = i / 9, t = i % 9;
            s_w[i] = w[((size_t)(ocBase + oc) * IC + ic) * 9 + t];
        }
        __syncthreads();
        float v[4][4];
#pragma unroll
        for (int r = 0; r < 4; ++r)
#pragma unroll
            for (int cc = 0; cc < 4; ++cc) v[r][cc] = s_in[(2 * ty + r) * 34 + (2 * tx + cc)];
#pragma unroll
        for (int oc = 0; oc < OCT; ++oc) {
#pragma unroll
            for (int ky = 0; ky < 3; ++ky)
#pragma unroll
                for (int kx = 0; kx < 3; ++kx) {
                    float wv = s_w[oc * 9 + ky * 3 + kx];
                    acc[oc][0] += wv * v[ky][kx];
                    acc[oc][1] += wv * v[ky][kx + 1];
                    acc[oc][2] += wv * v[ky + 1][kx];
                    acc[oc][3] += wv * v[ky + 1][kx + 1];
                }
        }
        __syncthreads();
    }
    int py = ty0 + 2 * ty, px = tx0 + 2 * tx;
#pragma unroll
    for (int oc = 0; oc < OCT; ++oc) {
        int og = ocBase + oc;
        float bv = bias[og];
        float osum = 0.f;
#pragma unroll
        for (int p = 0; p < 4; ++p) {
            int dy = p >> 1, dx = p & 1;
            float val = acc[oc][p] + bv;
            osum += val;
            out[(((size_t)b * 64 + og) * 64 + py + dy) * 64 + px + dx] = val;
            out_bf[(((size_t)b * 66 + py + dy + 1) * 66 + (px + dx + 1)) * 64 + og] = bf16u(val);
        }
        // wave reduce of osum
        for (int m = 1; m < 64; m <<= 1) osum += __shfl_xor(osum, m);
        if (lane == 0) wred[wid][oc] = osum;
    }
    __syncthreads();
    if (tid < OCT)
        atomicAdd(&hsum0[b * 64 + ocBase + tid],
                  wred[0][tid] + wred[1][tid] + wred[2][tid] + wred[3][tid]);
}

// ---------------------------------------------------------------------------
// Pixel shuffle + fused 5x5 skip conv + IMAGE_MEAN. out [8,3,128,128]
// ---------------------------------------------------------------------------
__global__ __launch_bounds__(256) void shuffle_skip(
    const float* __restrict__ body, const float* __restrict__ x,
    const float* __restrict__ skw, const float* __restrict__ skb,
    float* __restrict__ out) {
    __shared__ float w[900];
    __shared__ float bb[12];
    int tid = threadIdx.x;
    for (int i = tid; i < 900; i += 256) w[i] = skw[i];
    if (tid < 12) bb[tid] = skb[tid];
    __syncthreads();
    int idx = blockIdx.x * 256 + tid;
    int ox = idx & 127;
    int oy = (idx >> 7) & 127;
    int v = idx >> 14;
    int c = v % 3;
    int b = v / 3;
    int rx = ox & 1, ry = oy & 1;
    int xx = ox >> 1, yy = oy >> 1;
    int ch = c * 4 + ry * 2 + rx;
    float acc = bb[ch];
    for (int ic = 0; ic < 3; ++ic)
        for (int ky = 0; ky < 5; ++ky) {
            int gy = yy + ky - 2;
            if (gy < 0 || gy >= 64) continue;
            for (int kx = 0; kx < 5; ++kx) {
                int gx = xx + kx - 2;
                if (gx < 0 || gx >= 64) continue;
                acc += w[((ch * 3 + ic) * 5 + ky) * 5 + kx] *
                       (x[((size_t)(b * 3 + ic) * 64 + gy) * 64 + gx] - 0.5f);
            }
        }
    size_t src = (((size_t)b * 12 + ch) * 64 + yy) * 64 + xx;
    out[idx] = body[src] + acc + 0.5f;
}

// ---------------------------------------------------------------------------
extern "C" void kernel_launch(void* const* d_in, const int* in_sizes, int n_in,
                              void* d_out, int out_size, void* d_ws, size_t ws_size,
                              hipStream_t stream) {
    const float* x      = (const float*)d_in[0];
    const float* head_v = (const float*)d_in[1];
    const float* head_g = (const float*)d_in[2];
    const float* head_b = (const float*)d_in[3];
    const float* b1_v   = (const float*)d_in[4];
    const float* b1_g   = (const float*)d_in[5];
    const float* b1_b   = (const float*)d_in[6];
    const float* b1_mw  = (const float*)d_in[7];
    const float* b1_mb  = (const float*)d_in[8];
    const float* b2_v   = (const float*)d_in[9];
    const float* b2_g   = (const float*)d_in[10];
    const float* b2_b   = (const float*)d_in[11];
    const float* b2_mw  = (const float*)d_in[12];
    const float* b2_mb  = (const float*)d_in[13];
    const float* tail_v = (const float*)d_in[14];
    const float* tail_g = (const float*)d_in[15];
    const float* tail_b = (const float*)d_in[16];
    const float* skip_v = (const float*)d_in[17];
    const float* skip_g = (const float*)d_in[18];
    const float* skip_b = (const float*)d_in[19];

    float* ws = (float*)d_ws;
    size_t off = 0;
    auto alloc = [&](size_t n) { float* p = ws + off; off += (n + 3) & ~(size_t)3; return p; };
    float* head_w = alloc(64 * 27);
    float* tail_w = alloc(12 * 576);
    float* skip_w = alloc(12 * 75);
    float* b1_sc  = alloc(2048);
    float* b2_sc  = alloc(512);
    float* h      = alloc((size_t)8 * 64 * 4096);
    float* sums   = alloc(10240);   // hsum[4] @ l*512 ; tsum[4] @ 2048 + l*2048
    float* sbuf   = alloc(64);
    float* body   = alloc((size_t)8 * 12 * 4096);
    unsigned short* wq1  = (unsigned short*)alloc((size_t)8 * 256 * 576 / 2);
    unsigned short* wq2  = (unsigned short*)alloc((size_t)8 * 64 * 2304 / 2);
    unsigned short* wqt  = (unsigned short*)alloc(9216 / 2);
    unsigned short* h_bf = (unsigned short*)alloc((size_t)8 * 66 * 66 * 64 / 2);
    unsigned short* t_bf = (unsigned short*)alloc((size_t)8 * 66 * 66 * 256 / 2);
    (void)ws_size; (void)in_sizes; (void)n_in; (void)out_size;

    auto hsum = [&](int l) { return sums + l * 512; };
    auto tsum = [&](int l) { return sums + 2048 + l * 2048; };

    zero_all<<<335, 256, 0, stream>>>(h_bf, t_bf, sums);
    wn_all<<<2648, 256, 0, stream>>>(head_v, head_g, head_w, tail_v, tail_g, tail_w,
                                     skip_v, skip_g, skip_w, b1_v, b1_g, b1_sc,
                                     b2_v, b2_g, b2_sc);
    head_conv<<<dim3(4, 4, 8), 256, 0, stream>>>(x, head_w, head_b, h, h_bf, hsum(0));
    tail_repack<<<36, 256, 0, stream>>>(tail_w, wqt);

    for (int l = 0; l < 4; ++l) {
        // dyn conv 1: 64 -> 256, relu; fused routing softmax in combine
        combine_w2<<<4608, 256, 0, stream>>>(b1_v + (size_t)l * 512 * 576,
                                             b1_sc + (size_t)l * 512, hsum(l),
                                             b1_mw + (size_t)l * 8 * 64, b1_mb + l * 8,
                                             sbuf, wq1, 64, 64, 256, 64, 64);
        conv_mfma<64, 256, 64, 1, 4, 4, true, false, false, true, 256, true>
            <<<dim3(16, 4, 8), 256, 0, stream>>>(h_bf, wq1, b1_b + (size_t)l * 512, sbuf, 6,
                                                 nullptr, nullptr, t_bf, tsum(l), 147456);
        // dyn conv 2: 256 -> 64, +residual h; mean for next layer's routing
        combine_w2<<<4608, 256, 0, stream>>>(b2_v + (size_t)l * 128 * 2304,
                                             b2_sc + (size_t)l * 128, tsum(l),
                                             b2_mw + (size_t)l * 8 * 256, b2_mb + l * 8,
                                             sbuf, wq2, 16, 256, 64, 32, 256);
        conv_mfma<256, 64, 32, 2, 2, 2, false, true, true, true, 64, true>
            <<<dim3(32, 2, 8), 256, 0, stream>>>(t_bf, wq2, b2_b + (size_t)l * 128, sbuf, 4,
                                                 h, h, h_bf, (l < 3) ? hsum(l + 1) : nullptr,
                                                 147456);
    }

    // tail: 64 -> 12 via MFMA (padded to 16)
    conv_mfma<64, 16, 16, 1, 4, 4, false, false, true, false, 12, false>
        <<<dim3(16, 1, 8), 256, 0, stream>>>(h_bf, wqt, tail_b, nullptr, 0,
                                             nullptr, body, nullptr, nullptr, 0);
    // pixel shuffle + fused skip conv
    shuffle_skip<<<1536, 256, 0, stream>>>(body, x, skip_w, skip_b, (float*)d_out);
}